// Round 1
// 234.741 us; speedup vs baseline: 1.0028x; 1.0028x over previous
//
#include <hip/hip_runtime.h>

// FastVolterra1: out[r,:] = irfft(rfft(x[r,:]) * softmax(w1)), D=1024, fp32.
//
// Real-packed: z[n] = x[2n] + i*x[2n+1] (length 512);
//   Z = FFT_512(z);  W[k] = P[k]*Z[k] + i*q[k]*conj(Z[(512-k)%512]);
//   w = IFFT_512(W); out[2n]=Re w[n], out[2n+1]=Im w[n].
// P,q real, precomputed from softmax gate (1/512 norm folded in).
//
// FFT-512 = 3 radix-8 Stockham stages. 64 threads/row, 4 rows (=4 waves) per
// block; one row == one wave -> NO __syncthreads (same-wave LDS ops are
// in-order; empirically verified by earlier kernels passing barrier-free).
//
// R<this>: LDS now holds INTERLEAVED complex (float2) instead of separate
// re/im float arrays. Rationale: the kernel was LDS-issue-bound, not
// HBM-bound — 128 ds_*_b32 wave-ops/row at ~5.8cyc (issue-limited, 44 B/cyc)
// ~= 44us/CU vs the 40us HBM floor. Packing re+im into ds_*_b64 halves the
// op count (64 ops/row) at the same per-op cost (b64 ~ BW-limited 512B/op).
// Bank math: pad(e)=e+(e>>4) in float2 units, row stride 544 float2.
// A wave64 b64 op minimally touches each of the 32 banks 4x; all three
// access patterns below (p0+k, lt+68k, sb+8k+(k>>1)) were verified to hit
// every bank exactly 4x -> conflict-free minimum, same as the old b32 scheme.
// All pad formulas carry over unchanged: pad2(t+64k)=lt+68k,
// pad2((t&7)+64*(t>>3)+8k)=sb+8k+(k>>1).

#define R2F 0.70710678118654752f

// 8-point DFT, bins in natural order. Forward = e^{-2pi i/8}; INV conjugates.
template <bool INV>
__device__ __forceinline__ void bfly8(float* xr, float* xi)
{
    float t0r = xr[0] + xr[4], t0i = xi[0] + xi[4];
    float t1r = xr[0] - xr[4], t1i = xi[0] - xi[4];
    float t2r = xr[2] + xr[6], t2i = xi[2] + xi[6];
    float t3r = xr[2] - xr[6], t3i = xi[2] - xi[6];
    float e0r = t0r + t2r, e0i = t0i + t2i;
    float e2r = t0r - t2r, e2i = t0i - t2i;
    float e1r, e1i, e3r, e3i;
    if (!INV) { e1r = t1r + t3i; e1i = t1i - t3r; e3r = t1r - t3i; e3i = t1i + t3r; }
    else      { e1r = t1r - t3i; e1i = t1i + t3r; e3r = t1r + t3i; e3i = t1i - t3r; }
    float s0r = xr[1] + xr[5], s0i = xi[1] + xi[5];
    float s1r = xr[1] - xr[5], s1i = xi[1] - xi[5];
    float s2r = xr[3] + xr[7], s2i = xi[3] + xi[7];
    float s3r = xr[3] - xr[7], s3i = xi[3] - xi[7];
    float o0r = s0r + s2r, o0i = s0i + s2i;
    float o2r = s0r - s2r, o2i = s0i - s2i;
    float o1r, o1i, o3r, o3i;
    if (!INV) { o1r = s1r + s3i; o1i = s1i - s3r; o3r = s1r - s3i; o3i = s1i + s3r; }
    else      { o1r = s1r - s3i; o1i = s1i + s3r; o3r = s1r + s3i; o3i = s1i - s3r; }
    float p1r, p1i, p2r, p2i, p3r, p3i;
    if (!INV) {
        p1r = (o1r + o1i) * R2F;  p1i = (o1i - o1r) * R2F;
        p2r = o2i;                p2i = -o2r;
        p3r = (o3i - o3r) * R2F;  p3i = -(o3r + o3i) * R2F;
    } else {
        p1r = (o1r - o1i) * R2F;  p1i = (o1i + o1r) * R2F;
        p2r = -o2i;               p2i = o2r;
        p3r = -(o3r + o3i) * R2F; p3i = (o3r - o3i) * R2F;
    }
    xr[0] = e0r + o0r; xi[0] = e0i + o0i;
    xr[4] = e0r - o0r; xi[4] = e0i - o0i;
    xr[1] = e1r + p1r; xi[1] = e1i + p1i;
    xr[5] = e1r - p1r; xi[5] = e1i - p1i;
    xr[2] = e2r + p2r; xi[2] = e2i + p2i;
    xr[6] = e2r - p2r; xi[6] = e2i - p2i;
    xr[3] = e3r + p3r; xi[3] = e3i + p3i;
    xr[7] = e3r - p3r; xi[7] = e3i - p3i;
}

// Tables store (cos th, sin th), th >= 0. Forward multiplies by e^{-i th}.
template <bool INV>
__device__ __forceinline__ void tw_apply(float* xr, float* xi,
                                         const float* c, const float* s)
{
#pragma unroll
    for (int k = 1; k < 8; ++k) {
        float r, i;
        if (!INV) { r = xr[k] * c[k] + xi[k] * s[k]; i = xi[k] * c[k] - xr[k] * s[k]; }
        else      { r = xr[k] * c[k] - xi[k] * s[k]; i = xi[k] * c[k] + xr[k] * s[k]; }
        xr[k] = r; xi[k] = i;
    }
}

__global__ __launch_bounds__(256)
void fv_kernel(const float2* __restrict__ x,
               const float2* __restrict__ pq,    // (P[k], q[k]) k=0..511
               const float2* __restrict__ tw1,   // [(k-1)*64 + t], k=1..7
               const float2* __restrict__ tw8,   // [(k-1)*8 + p],  k=1..7
               float2* __restrict__ out)
{
    __shared__ float2 sz[4][544];                // interleaved complex, padded
    const int tid = threadIdx.x;
    const int r = tid >> 6;      // row within block == wave id
    const int t = tid & 63;      // lane
    float2* sh = sz[r];
    const size_t rowbase = ((size_t)blockIdx.x * 4 + r) * 512;  // float2 units

    // twiddle register sets (k=1..7)
    float c1[8], s1[8], c8[8], s8[8];
#pragma unroll
    for (int k = 1; k < 8; ++k) {
        float2 w = tw1[(k - 1) * 64 + t];        c1[k] = w.x; s1[k] = w.y;
        float2 v = tw8[(k - 1) * 8 + (t >> 3)];  c8[k] = v.x; s8[k] = v.y;
    }

    // padded-address bases (float2 units): pad(e) = e + (e>>4), row stride 544
    const int p0 = (t << 3) + (t >> 1);          // pad(8t); 8t..8t+7 stay consecutive
    const int lt = t + (t >> 4);                 // pad(t + 64k) = lt + 68k
    const int sb = (t & 7) + 68 * (t >> 3);      // pad(S=8 store base)

    float zr[8], zi[8];

    // ---- forward FFT-512 ----
#pragma unroll
    for (int k = 0; k < 8; ++k) {
        float2 v = x[rowbase + t + 64 * k];
        zr[k] = v.x; zi[k] = v.y;
    }
    bfly8<false>(zr, zi);
    tw_apply<false>(zr, zi, c1, s1);
#pragma unroll
    for (int k = 0; k < 8; ++k) sh[p0 + k] = make_float2(zr[k], zi[k]);
#pragma unroll
    for (int k = 0; k < 8; ++k) {
        float2 v = sh[lt + 68 * k];
        zr[k] = v.x; zi[k] = v.y;
    }
    bfly8<false>(zr, zi);
    tw_apply<false>(zr, zi, c8, s8);
#pragma unroll
    for (int k = 0; k < 8; ++k) {
        int a = sb + 8 * k + (k >> 1);
        sh[a] = make_float2(zr[k], zi[k]);
    }
#pragma unroll
    for (int k = 0; k < 8; ++k) {
        float2 v = sh[lt + 68 * k];
        zr[k] = v.x; zi[k] = v.y;
    }
    bfly8<false>(zr, zi);
    // regs now hold Z[t + 64k] in natural order.

    // ---- combine W = P*Z + i*q*conj(Z_mirror), all in regs + shfl ----
    {
        const int src = (64 - t) & 63;
        float vr[8], vi[8];
#pragma unroll
        for (int k = 0; k < 8; ++k) {
            vr[k] = __shfl(zr[7 - k], src, 64);
            vi[k] = __shfl(zi[7 - k], src, 64);
        }
        if (t == 0) {
#pragma unroll
            for (int k = 0; k < 8; ++k) {
                int kk = (8 - k) & 7;
                vr[k] = zr[kk]; vi[k] = zi[kk];
            }
        }
#pragma unroll
        for (int k = 0; k < 8; ++k) {
            float2 g = pq[t + 64 * k];
            float nr = g.x * zr[k] + g.y * vi[k];
            float ni = g.x * zi[k] + g.y * vr[k];
            zr[k] = nr; zi[k] = ni;
        }
    }

    // ---- inverse FFT-512 (input already in stage-1 read layout) ----
    bfly8<true>(zr, zi);
    tw_apply<true>(zr, zi, c1, s1);
#pragma unroll
    for (int k = 0; k < 8; ++k) sh[p0 + k] = make_float2(zr[k], zi[k]);
#pragma unroll
    for (int k = 0; k < 8; ++k) {
        float2 v = sh[lt + 68 * k];
        zr[k] = v.x; zi[k] = v.y;
    }
    bfly8<true>(zr, zi);
    tw_apply<true>(zr, zi, c8, s8);
#pragma unroll
    for (int k = 0; k < 8; ++k) {
        int a = sb + 8 * k + (k >> 1);
        sh[a] = make_float2(zr[k], zi[k]);
    }
#pragma unroll
    for (int k = 0; k < 8; ++k) {
        float2 v = sh[lt + 68 * k];
        zr[k] = v.x; zi[k] = v.y;
    }
    bfly8<true>(zr, zi);
#pragma unroll
    for (int k = 0; k < 8; ++k) {
        out[rowbase + t + 64 * k] = make_float2(zr[k], zi[k]);
    }
}

// Build softmax gate -> (P,q) table and twiddle tables, all in d_ws.
__global__ void gate_kernel(const float* __restrict__ w1,
                            float2* __restrict__ pq,
                            float2* __restrict__ tw1,
                            float2* __restrict__ tw8)
{
    __shared__ float red[1024];
    __shared__ float ex[513];
    const int t = threadIdx.x;  // 1024 threads

    float v = (t < 513) ? w1[t] : -1e30f;
    red[t] = v;
    __syncthreads();
    for (int off = 512; off > 0; off >>= 1) {
        if (t < off) red[t] = fmaxf(red[t], red[t + off]);
        __syncthreads();
    }
    float M = red[0];
    __syncthreads();

    float e = (t < 513) ? expf(w1[t] - M) : 0.0f;
    if (t < 513) ex[t] = e;
    red[t] = e;
    __syncthreads();
    for (int off = 512; off > 0; off >>= 1) {
        if (t < off) red[t] += red[t + off];
        __syncthreads();
    }
    float inv = 1.0f / red[0];
    __syncthreads();

    if (t < 512) {
        float ga = ex[t] * inv;
        float gb = ex[512 - t] * inv;
        float gp = ga + gb, gm = ga - gb;
        float th = (float)t * 6.13592315154256492e-03f;  // pi/512 * t = 2*pi*t/1024
        float sn, cs;
        __sincosf(th, &sn, &cs);
        float P = 0.5f * (gp - gm * sn) * (1.0f / 512.0f);
        float q = 0.5f * (gm * cs) * (1.0f / 512.0f);
        pq[t] = make_float2(P, q);
    }
    if (t < 448) {
        int k = (t >> 6) + 1;
        int j = t & 63;
        float th = (float)(j * k) * 1.22718463151036952e-02f;  // 2*pi/512
        float sn, cs;
        sincosf(th, &sn, &cs);
        tw1[t] = make_float2(cs, sn);
    }
    if (t < 56) {
        int k = (t >> 3) + 1;
        int p = t & 7;
        float th = (float)(p * k) * 9.81747704246810387e-02f;  // 2*pi/64
        float sn, cs;
        sincosf(th, &sn, &cs);
        tw8[t] = make_float2(cs, sn);
    }
}

extern "C" void kernel_launch(void* const* d_in, const int* in_sizes, int n_in,
                              void* d_out, int out_size, void* d_ws, size_t ws_size,
                              hipStream_t stream)
{
    (void)n_in; (void)out_size; (void)ws_size;
    const float2* hidden = (const float2*)d_in[0];   // [32768 rows, 512 float2]
    const float*  w1     = (const float*)d_in[1];    // [513]
    float2* out = (float2*)d_out;

    float2* pq  = (float2*)d_ws;          // 512 float2
    float2* tw1 = pq + 512;               // 448 float2
    float2* tw8 = tw1 + 448;              // 56  float2

    gate_kernel<<<1, 1024, 0, stream>>>(w1, pq, tw1, tw8);

    const int rows   = in_sizes[0] / 1024;   // 32768
    const int blocks = rows / 4;             // 8192
    fv_kernel<<<blocks, 256, 0, stream>>>(hidden, pq, tw1, tw8, out);
}